// Round 1
// baseline (80.111 us; speedup 1.0000x reference)
//
#include <hip/hip_runtime.h>

// MultiPositiveContrastiveLoss: B=32768 problems, C=64 candidates, P=16 pos, N=48 neg.
// One wave per problem-slot: lanes 48..63 hold pos scores, lanes 0..47 hold neg scores.
// Inner loop broadcasts pos_i via __shfl; invalid negs carry -1e30 so relu term is 0.

#define MARGIN 0.5f

constexpr int C = 64;
constexpr int P = 16;
constexpr int N = 48;
constexpr int BLOCK = 256;
constexpr int WAVES_PER_BLOCK = BLOCK / 64;      // 4
constexpr int PROBS_PER_WAVE = 4;
constexpr int PROBS_PER_BLOCK = WAVES_PER_BLOCK * PROBS_PER_WAVE;  // 16

__global__ __launch_bounds__(BLOCK) void mpcl_partial_kernel(
    const float* __restrict__ scores,
    const int*   __restrict__ pos_indices,
    const int*   __restrict__ neg_indices,
    const int*   __restrict__ pos_counts,
    const int*   __restrict__ neg_counts,
    float2*      __restrict__ partials,
    int B)
{
    const int lane = threadIdx.x & 63;
    const int wave = threadIdx.x >> 6;

    float tot = 0.0f;
    float cnt = 0.0f;

    const int b0 = (blockIdx.x * WAVES_PER_BLOCK + wave) * PROBS_PER_WAVE;

    for (int k = 0; k < PROBS_PER_WAVE; ++k) {
        const int b = b0 + k;
        if (b >= B) break;

        const int pc = pos_counts[b];   // wave-uniform scalar load
        const int nc = neg_counts[b];

        // lanes 48..63: positive slot (lane-48); lanes 0..47: negative slot (lane)
        float myval  = 0.0f;     // pos score for lanes >= 48
        float negval = -1e30f;   // invalid neg contributes relu(-inf)=0
        if (lane >= 48) {
            const int idx = pos_indices[b * P + (lane - 48)];  // idx in [0,C)
            myval = scores[b * C + idx];
        } else if (lane < nc) {
            const int idx = neg_indices[b * N + lane];
            negval = scores[b * C + idx];
        }

        float s = 0.0f;
        for (int i = 0; i < pc; ++i) {               // pc <= 16, wave-uniform
            const float pos_i = __shfl(myval, 48 + i);
            s += fmaxf(MARGIN - pos_i + negval, 0.0f);
        }
        tot += s;
        cnt += (float)(pc * nc);                     // closed-form pair count
    }

    // wave reduce total (count is wave-uniform already)
    #pragma unroll
    for (int off = 32; off; off >>= 1) tot += __shfl_xor(tot, off);

    __shared__ float2 lds[WAVES_PER_BLOCK];
    if (lane == 0) lds[wave] = make_float2(tot, cnt);
    __syncthreads();

    if (threadIdx.x == 0) {
        float2 acc = lds[0];
        #pragma unroll
        for (int w = 1; w < WAVES_PER_BLOCK; ++w) { acc.x += lds[w].x; acc.y += lds[w].y; }
        partials[blockIdx.x] = acc;
    }
}

__global__ __launch_bounds__(BLOCK) void mpcl_final_kernel(
    const float2* __restrict__ partials, int n, float* __restrict__ out)
{
    float tot = 0.0f, cnt = 0.0f;
    for (int i = threadIdx.x; i < n; i += BLOCK) {
        const float2 p = partials[i];
        tot += p.x;
        cnt += p.y;
    }
    #pragma unroll
    for (int off = 32; off; off >>= 1) {
        tot += __shfl_xor(tot, off);
        cnt += __shfl_xor(cnt, off);
    }

    __shared__ float2 lds[WAVES_PER_BLOCK];
    const int wave = threadIdx.x >> 6;
    const int lane = threadIdx.x & 63;
    if (lane == 0) lds[wave] = make_float2(tot, cnt);
    __syncthreads();

    if (threadIdx.x == 0) {
        float T = 0.0f, Cn = 0.0f;
        #pragma unroll
        for (int w = 0; w < WAVES_PER_BLOCK; ++w) { T += lds[w].x; Cn += lds[w].y; }
        out[0] = (Cn > 0.0f) ? (T / fmaxf(Cn, 1.0f)) : 0.0f;
    }
}

extern "C" void kernel_launch(void* const* d_in, const int* in_sizes, int n_in,
                              void* d_out, int out_size, void* d_ws, size_t ws_size,
                              hipStream_t stream) {
    const float* scores      = (const float*)d_in[0];
    const int*   pos_indices = (const int*)d_in[1];
    const int*   neg_indices = (const int*)d_in[2];
    const int*   pos_counts  = (const int*)d_in[3];
    const int*   neg_counts  = (const int*)d_in[4];
    float*       out         = (float*)d_out;

    const int B = in_sizes[3];                       // 32768
    const int grid = (B + PROBS_PER_BLOCK - 1) / PROBS_PER_BLOCK;  // 2048

    float2* partials = (float2*)d_ws;                // 2048 * 8 B = 16 KB

    mpcl_partial_kernel<<<grid, BLOCK, 0, stream>>>(
        scores, pos_indices, neg_indices, pos_counts, neg_counts, partials, B);
    mpcl_final_kernel<<<1, BLOCK, 0, stream>>>(partials, grid, out);
}